// Round 8
// baseline (174.078 us; speedup 1.0000x reference)
//
#include <hip/hip_runtime.h>
#include <hip/hip_cooperative_groups.h>
#include <math.h>

namespace cg = cooperative_groups;

#define NB 4
#define NT 128
#define NS 512
#define NH 256

// pe/pq prescaled by 2*log2(e) so exp(2z) == exp2(pe'+pq')
#define SCALE_2LOG2E 2.8853900817779268f

__device__ __forceinline__ float fast_exp2(float x) {
#if __has_builtin(__builtin_amdgcn_exp2f)
    return __builtin_amdgcn_exp2f(x);
#else
    return __expf(x * 0.6931471805599453f);
#endif
}

__device__ __forceinline__ float fast_tanh(float x) {
    // tanh(x) = 1 - 2/(exp(2x)+1); safe at +/-inf
    float e = __expf(2.0f * x);
    return 1.0f - 2.0f / (e + 1.0f);
}

__device__ __forceinline__ float dot4(float4 a, float4 b, float acc) {
    acc = fmaf(a.x, b.x, acc);
    acc = fmaf(a.y, b.y, acc);
    acc = fmaf(a.z, b.z, acc);
    acc = fmaf(a.w, b.w, acc);
    return acc;
}

// ---------------------------------------------------------------------------
// Phase 1 (units 0..319): projections, prescaled by 2*log2e.
//   u < 256:        peT[b][o][s] = scale*(enc[b,s,:].Wh[o,:])  (transposed
//                   via LDS bounce; tl aliases wsh after a barrier)
//   u in [256,320): pq[r][o] = scale*(q[r,:].Ws[o,:])
// W tile (64 o x 256 k) LDS-staged XOR-swizzled; X rows wave-uniform s_loads.
// ---------------------------------------------------------------------------
__device__ __forceinline__ void phase1(
    unsigned char* smem, int u, int tid,
    const float* __restrict__ enc, const float* __restrict__ q,
    const float* __restrict__ Wh, const float* __restrict__ Ws,
    const float* __restrict__ v,
    float* __restrict__ peT, float* __restrict__ pq, float* __restrict__ w)
{
    float4* wsh = reinterpret_cast<float4*>(smem);   // 64 KB
    float*  tl  = reinterpret_cast<float*>(smem);    // 9 KB, reused post-barrier

    const bool is_pe = (u < 256);
    const int mt = is_pe ? (u >> 2) : ((u - 256) >> 2);
    const int ot = u & 3;
    const float* __restrict__ X = is_pe ? enc : q;
    const float* __restrict__ W = is_pe ? Wh : Ws;
    const int r0 = mt * 32;

    if (u == 256 && tid < NH) w[tid] = -2.0f * v[tid];

    // stage W tile: 64 rows x 64 f4, XOR-swizzled low-3
    {
        const int row = tid >> 3, jl = tid & 7;
        const float4* src = reinterpret_cast<const float4*>(W + (size_t)(ot * 64 + row) * NH);
        const int rsw = row & 7;
#pragma unroll
        for (int kk = 0; kk < 8; ++kk) {
            const int j = jl + 8 * kk;
            wsh[row * 64 + (j ^ rsw)] = src[j];
        }
    }
    __syncthreads();

    const int o  = tid & 63;
    const int wv = __builtin_amdgcn_readfirstlane(tid >> 6);
    const int m0 = r0 + wv * 4;

    const float4* __restrict__ x0 = reinterpret_cast<const float4*>(X + (size_t)(m0 + 0) * NH);
    const float4* __restrict__ x1 = reinterpret_cast<const float4*>(X + (size_t)(m0 + 1) * NH);
    const float4* __restrict__ x2 = reinterpret_cast<const float4*>(X + (size_t)(m0 + 2) * NH);
    const float4* __restrict__ x3 = reinterpret_cast<const float4*>(X + (size_t)(m0 + 3) * NH);

    float a0 = 0.f, a1 = 0.f, a2 = 0.f, a3 = 0.f;
    const int osw = o & 7;
#pragma unroll 8
    for (int k4 = 0; k4 < 64; ++k4) {
        const float4 wq = wsh[o * 64 + (k4 ^ osw)];
        a0 = dot4(wq, x0[k4], a0);
        a1 = dot4(wq, x1[k4], a1);
        a2 = dot4(wq, x2[k4], a2);
        a3 = dot4(wq, x3[k4], a3);
    }

    if (!is_pe) {
        const int oc = ot * 64 + o;
        pq[(size_t)(m0 + 0) * NH + oc] = a0 * SCALE_2LOG2E;
        pq[(size_t)(m0 + 1) * NH + oc] = a1 * SCALE_2LOG2E;
        pq[(size_t)(m0 + 2) * NH + oc] = a2 * SCALE_2LOG2E;
        pq[(size_t)(m0 + 3) * NH + oc] = a3 * SCALE_2LOG2E;
    } else {
        __syncthreads();   // wsh dead -> tl may alias it
        const int ml = wv * 4;
        tl[o * 36 + ml + 0] = a0 * SCALE_2LOG2E;
        tl[o * 36 + ml + 1] = a1 * SCALE_2LOG2E;
        tl[o * 36 + ml + 2] = a2 * SCALE_2LOG2E;
        tl[o * 36 + ml + 3] = a3 * SCALE_2LOG2E;
        __syncthreads();
        const int row = tid >> 3, jl = tid & 7;   // row = o-local, jl*4 = s-local
        const int b = r0 >> 9, s0 = r0 & (NS - 1);
        const float4 v4 = *reinterpret_cast<const float4*>(&tl[row * 36 + jl * 4]);
        *reinterpret_cast<float4*>(
            peT + ((size_t)b * NH + ot * 64 + row) * NS + s0 + jl * 4) = v4;
    }
}

// ---------------------------------------------------------------------------
// Phase 2 (units 0..511): e'[t,s] = sum_h w[h]/(exp2(peT[b,h,s]+pq[t,h])+1)
// No LDS; peT rows read lane-coalesced; pq/w wave-uniform s_loads.
// 8 waves = 8 t-rows, lanes = 64 s.
// ---------------------------------------------------------------------------
__device__ __forceinline__ void phase2(
    int u, int tid,
    const float* __restrict__ peT, const float* __restrict__ pq,
    const float* __restrict__ w, float* __restrict__ e)
{
    const int sx = u & 7;
    const int ty = (u >> 3) & 15;
    const int b  = u >> 7;
    const int lane = tid & 63;
    const int wv = __builtin_amdgcn_readfirstlane(tid >> 6);
    const int t = ty * 8 + wv;
    const int s = sx * 64 + lane;

    const float4* __restrict__ pqp = reinterpret_cast<const float4*>(
        pq + (size_t)(b * NT + t) * NH);
    const float4* __restrict__ wp = reinterpret_cast<const float4*>(w);
    const float* __restrict__ pp0 = peT + (size_t)b * NH * NS + s;

    float acc = 0.f;
#pragma unroll 4
    for (int h4 = 0; h4 < 64; ++h4) {
        const float4 a  = pqp[h4];
        const float4 wl = wp[h4];
        const float* pp = pp0 + (size_t)(4 * h4) * NS;
        const float p0 = pp[0], p1 = pp[NS], p2 = pp[2 * NS], p3 = pp[3 * NS];
        acc = fmaf(wl.x, __builtin_amdgcn_rcpf(fast_exp2(p0 + a.x) + 1.0f), acc);
        acc = fmaf(wl.y, __builtin_amdgcn_rcpf(fast_exp2(p1 + a.y) + 1.0f), acc);
        acc = fmaf(wl.z, __builtin_amdgcn_rcpf(fast_exp2(p2 + a.z) + 1.0f), acc);
        acc = fmaf(wl.w, __builtin_amdgcn_rcpf(fast_exp2(p3 + a.w) + 1.0f), acc);
    }
    e[(size_t)(b * NT + t) * NS + s] = acc;
}

// ---------------------------------------------------------------------------
// Phase 3 (units 0..255): masked softmax + context. 8 waves = 8 t-rows,
// lanes = 64 h (tile ht). Softmax in-register; alpha rows in LDS; enc
// chunks (128 s x 64 h = 32 KB) staged in LDS so enc is read ONCE per block.
// ---------------------------------------------------------------------------
__device__ __forceinline__ void phase3(
    unsigned char* smem, int u, int tid,
    const float* __restrict__ e, const float* __restrict__ enc,
    const int* __restrict__ lens, float* __restrict__ c)
{
    float* shE   = reinterpret_cast<float*>(smem);           // 32 KB
    float* alpha = reinterpret_cast<float*>(smem + 32768);   // 16 KB: 8 x 512
    float* rs    = reinterpret_cast<float*>(smem + 49152);   // 8 floats

    const int ht = u & 3;
    const int tt = (u >> 2) & 15;
    const int b  = u >> 6;
    const int lane = tid & 63;
    const int wv = __builtin_amdgcn_readfirstlane(tid >> 6);
    const int t = tt * 8 + wv;
    const int len = lens[b];

    // --- in-register masked softmax of row t (8 vals/lane) ---
    const float4* erow = reinterpret_cast<const float4*>(e + (size_t)(b * NT + t) * NS);
    float4 va = erow[lane];
    float4 vb = erow[lane + 64];
    const int c0 = 4 * lane;
    const int c1 = 256 + 4 * lane;
    if (c0 + 0 >= len) va.x = -INFINITY;
    if (c0 + 1 >= len) va.y = -INFINITY;
    if (c0 + 2 >= len) va.z = -INFINITY;
    if (c0 + 3 >= len) va.w = -INFINITY;
    if (c1 + 0 >= len) vb.x = -INFINITY;
    if (c1 + 1 >= len) vb.y = -INFINITY;
    if (c1 + 2 >= len) vb.z = -INFINITY;
    if (c1 + 3 >= len) vb.w = -INFINITY;

    float m = fmaxf(fmaxf(fmaxf(va.x, va.y), fmaxf(va.z, va.w)),
                    fmaxf(fmaxf(vb.x, vb.y), fmaxf(vb.z, vb.w)));
#pragma unroll
    for (int off = 32; off; off >>= 1) m = fmaxf(m, __shfl_xor(m, off));

    va.x = __expf(va.x - m); va.y = __expf(va.y - m);
    va.z = __expf(va.z - m); va.w = __expf(va.w - m);
    vb.x = __expf(vb.x - m); vb.y = __expf(vb.y - m);
    vb.z = __expf(vb.z - m); vb.w = __expf(vb.w - m);

    float sum = va.x + va.y + va.z + va.w + vb.x + vb.y + vb.z + vb.w;
#pragma unroll
    for (int off = 32; off; off >>= 1) sum += __shfl_xor(sum, off);
    if (lane == 0) rs[wv] = 1.0f / sum;

    float4* arow = reinterpret_cast<float4*>(alpha + wv * NS);
    arow[lane] = va;
    arow[lane + 64] = vb;
    __syncthreads();
    const float rsum = rs[wv];

    // --- context over 4 enc chunks staged in LDS ---
    const float* encb = enc + (size_t)b * NS * NH + ht * 64;
    float acc = 0.f;
#pragma unroll 1
    for (int ch = 0; ch < 4; ++ch) {
        // stage chunk: rows ch*128..+128, 64 h-cols; f1 coalesced, bank-free
#pragma unroll
        for (int pass = 0; pass < 16; ++pass) {
            const int row = pass * 8 + wv;
            shE[row * 64 + lane] = encb[(size_t)(ch * 128 + row) * NH + lane];
        }
        __syncthreads();
        const float4* a4 = reinterpret_cast<const float4*>(alpha + wv * NS + ch * 128);
#pragma unroll 8
        for (int j = 0; j < 32; ++j) {
            const float4 al = a4[j];
            const float* er = shE + (4 * j) * 64 + lane;
            acc = fmaf(al.x, er[0],   acc);
            acc = fmaf(al.y, er[64],  acc);
            acc = fmaf(al.z, er[128], acc);
            acc = fmaf(al.w, er[192], acc);
        }
        __syncthreads();
    }
    c[(size_t)(b * NT + t) * NH + ht * 64 + lane] = acc * rsum;
}

// ---------------------------------------------------------------------------
// Phase 4 (units 0..255): out[bt,o] = tanh(cat[bt,:].Wout[o,:]), cat=[q|c].
// Wout half-tiles (64 o x 256 k) staged swizzled; cat rows wave-uniform.
// ---------------------------------------------------------------------------
__device__ __forceinline__ void phase4(
    unsigned char* smem, int u, int tid,
    const float* __restrict__ qin, const float* __restrict__ cin,
    const float* __restrict__ Wout, float* __restrict__ out)
{
    float4* wsh = reinterpret_cast<float4*>(smem);

    const int ot  = u & 3;
    const int btt = u >> 2;
    const int o   = tid & 63;
    const int wv  = __builtin_amdgcn_readfirstlane(tid >> 6);
    const int bt  = btt * 8 + wv;
    const int osw = o & 7;

    float acc = 0.f;
#pragma unroll
    for (int half = 0; half < 2; ++half) {
        __syncthreads();
        {
            const int row = tid >> 3, jl = tid & 7;
            const float4* src = reinterpret_cast<const float4*>(
                Wout + (size_t)(ot * 64 + row) * (2 * NH) + half * NH);
            const int rsw = row & 7;
#pragma unroll
            for (int kk = 0; kk < 8; ++kk) {
                const int j = jl + 8 * kk;
                wsh[row * 64 + (j ^ rsw)] = src[j];
            }
        }
        __syncthreads();

        const float4* __restrict__ xr = reinterpret_cast<const float4*>(
            (half ? cin : qin) + (size_t)bt * NH);
#pragma unroll 8
        for (int k4 = 0; k4 < 64; ++k4) {
            acc = dot4(wsh[o * 64 + (k4 ^ osw)], xr[k4], acc);
        }
    }
    out[(size_t)bt * NH + ot * 64 + o] = fast_tanh(acc);
}

// ---------------------------------------------------------------------------
// Cooperative mega-kernel: 256 blocks x 512 threads (co-residency-safe under
// ANY occupancy >= 1 block/CU), 64 KB LDS union. Phases grid-stride their
// work units; __syncthreads guards LDS reuse between serial units.
// ---------------------------------------------------------------------------
__global__ __launch_bounds__(512) void mega(
    const float* __restrict__ enc, const float* __restrict__ q,
    const int* __restrict__ lens,
    const float* __restrict__ Wh, const float* __restrict__ Ws,
    const float* __restrict__ v, const float* __restrict__ Wout,
    float* __restrict__ peT, float* __restrict__ pq, float* __restrict__ w,
    float* __restrict__ e, float* __restrict__ c, float* __restrict__ out)
{
    __shared__ __align__(16) unsigned char smem[65536];
    cg::grid_group grid = cg::this_grid();
    const int bx = blockIdx.x;
    const int tid = threadIdx.x;

    // phase 1: 320 units over 256 blocks
    for (int u = bx; u < 320; u += 256) {
        __syncthreads();
        phase1(smem, u, tid, enc, q, Wh, Ws, v, peT, pq, w);
    }
    grid.sync();
    // phase 2: 512 units, 2 per block (no LDS)
    phase2(2 * bx + 0, tid, peT, pq, w, e);
    phase2(2 * bx + 1, tid, peT, pq, w, e);
    grid.sync();
    // phase 3: 256 units
    phase3(smem, bx, tid, e, enc, lens, c);
    grid.sync();
    // phase 4: 256 units
    phase4(smem, bx, tid, q, c, Wout, out);
}

extern "C" void kernel_launch(void* const* d_in, const int* in_sizes, int n_in,
                              void* d_out, int out_size, void* d_ws, size_t ws_size,
                              hipStream_t stream) {
    const float* q    = (const float*)d_in[0];  // (B,T,H)
    const float* enc  = (const float*)d_in[1];  // (B,S,H)
    const int*   lens = (const int*)d_in[2];    // (B,)
    const float* Ws   = (const float*)d_in[3];  // (H,H)
    const float* Wh   = (const float*)d_in[4];  // (H,H)
    const float* v    = (const float*)d_in[5];  // (H,)
    const float* Wout = (const float*)d_in[6];  // (H,2H)
    float* out = (float*)d_out;                 // (B,T,H)

    float* peT = (float*)d_ws;                        // NB*NH*NS
    float* pq  = peT + (size_t)NB * NH * NS;          // NB*NT*NH
    float* w   = pq  + (size_t)NB * NT * NH;          // NH
    float* e   = w + NH;                              // NB*NT*NS
    float* c   = e + (size_t)NB * NT * NS;            // NB*NT*NH

    void* args[] = { (void*)&enc, (void*)&q, (void*)&lens, (void*)&Wh,
                     (void*)&Ws, (void*)&v, (void*)&Wout,
                     (void*)&peT, (void*)&pq, (void*)&w,
                     (void*)&e, (void*)&c, (void*)&out };
    hipLaunchCooperativeKernel(reinterpret_cast<void*>(mega),
                               dim3(256), dim3(512), args, 0, stream);
}

// Round 9
// 65.957 us; speedup vs baseline: 2.6393x; 2.6393x over previous
//
#include <hip/hip_runtime.h>
#include <math.h>

#define NB 4
#define NT 128
#define NS 512
#define NH 256

// pe/pq prescaled by 2*log2(e) so exp(2z) == exp2(pe'+pq')
#define SCALE_2LOG2E 2.8853900817779268f

__device__ __forceinline__ float fast_exp2(float x) {
#if __has_builtin(__builtin_amdgcn_exp2f)
    return __builtin_amdgcn_exp2f(x);
#else
    return __expf(x * 0.6931471805599453f);
#endif
}

__device__ __forceinline__ float fast_tanh(float x) {
    // tanh(x) = 1 - 2/(exp(2x)+1); safe at +/-inf
    float e = __expf(2.0f * x);
    return 1.0f - 2.0f / (e + 1.0f);
}

__device__ __forceinline__ float dot4(float4 a, float4 b, float acc) {
    acc = fmaf(a.x, b.x, acc);
    acc = fmaf(a.y, b.y, acc);
    acc = fmaf(a.z, b.z, acc);
    acc = fmaf(a.w, b.w, acc);
    return acc;
}

// ---------------------------------------------------------------------------
// K1: projections, prescaled by 2*log2e.
//   bx < 256:        peP[b][h/4][s] (float4 over h-quad) = enc[b,s,:].Wh[h,:]
//                    -- packed via LDS bounce so K2 reads ONE f4 per (s,h4)
//   bx in [256,320): pq[r][o] = scale*(q[r,:].Ws[o,:])  (row-major)
// W tile (64 o x 256 k) LDS-staged XOR-swizzled; X rows wave-uniform s_loads.
// Block 256 also writes w = -2v.
// ---------------------------------------------------------------------------
__global__ __launch_bounds__(512) void k1_proj(
    const float* __restrict__ enc, const float* __restrict__ q,
    const float* __restrict__ Wh, const float* __restrict__ Ws,
    const float* __restrict__ v,
    float4* __restrict__ peP, float* __restrict__ pq, float* __restrict__ w)
{
    __shared__ float4 wsh[64 * 64];   // 64 KB
    __shared__ float tl[64 * 36];     // 9 KB transpose bounce (pad 36)

    const int bx = blockIdx.x;
    const int tid = threadIdx.x;
    const bool is_pe = (bx < 256);
    const int mt = is_pe ? (bx >> 2) : ((bx - 256) >> 2);
    const int ot = bx & 3;
    const float* __restrict__ X = is_pe ? enc : q;
    const float* __restrict__ W = is_pe ? Wh : Ws;
    const int r0 = mt * 32;

    if (bx == 256 && tid < NH) w[tid] = -2.0f * v[tid];

    // stage W tile: 64 rows x 64 f4, XOR-swizzled low-3
    {
        const int row = tid >> 3, jl = tid & 7;
        const float4* src = reinterpret_cast<const float4*>(W + (size_t)(ot * 64 + row) * NH);
        const int rsw = row & 7;
#pragma unroll
        for (int kk = 0; kk < 8; ++kk) {
            const int j = jl + 8 * kk;
            wsh[row * 64 + (j ^ rsw)] = src[j];
        }
    }
    __syncthreads();

    const int o  = tid & 63;
    const int wv = __builtin_amdgcn_readfirstlane(tid >> 6);  // 0..7
    const int m0 = r0 + wv * 4;

    const float4* __restrict__ x0 = reinterpret_cast<const float4*>(X + (size_t)(m0 + 0) * NH);
    const float4* __restrict__ x1 = reinterpret_cast<const float4*>(X + (size_t)(m0 + 1) * NH);
    const float4* __restrict__ x2 = reinterpret_cast<const float4*>(X + (size_t)(m0 + 2) * NH);
    const float4* __restrict__ x3 = reinterpret_cast<const float4*>(X + (size_t)(m0 + 3) * NH);

    float a0 = 0.f, a1 = 0.f, a2 = 0.f, a3 = 0.f;
    const int osw = o & 7;
#pragma unroll 8
    for (int k4 = 0; k4 < 64; ++k4) {
        const float4 wq = wsh[o * 64 + (k4 ^ osw)];
        a0 = dot4(wq, x0[k4], a0);
        a1 = dot4(wq, x1[k4], a1);
        a2 = dot4(wq, x2[k4], a2);
        a3 = dot4(wq, x3[k4], a3);
    }

    if (!is_pe) {
        const int oc = ot * 64 + o;
        pq[(size_t)(m0 + 0) * NH + oc] = a0 * SCALE_2LOG2E;
        pq[(size_t)(m0 + 1) * NH + oc] = a1 * SCALE_2LOG2E;
        pq[(size_t)(m0 + 2) * NH + oc] = a2 * SCALE_2LOG2E;
        pq[(size_t)(m0 + 3) * NH + oc] = a3 * SCALE_2LOG2E;
    } else {
        __syncthreads();   // wsh dead beyond this point (tl is separate; keep order)
        // tl[o_local][s_local]: o_local = h within ot-tile, s_local = row 0..31
        const int ml = wv * 4;
        tl[o * 36 + ml + 0] = a0 * SCALE_2LOG2E;
        tl[o * 36 + ml + 1] = a1 * SCALE_2LOG2E;
        tl[o * 36 + ml + 2] = a2 * SCALE_2LOG2E;
        tl[o * 36 + ml + 3] = a3 * SCALE_2LOG2E;
        __syncthreads();
        // repack: thread = (hq_l 0..15, s_l 0..31) -> f4 of h-quad
        const int hq_l = tid >> 5, s_l = tid & 31;
        const int b = r0 >> 9, s0 = r0 & (NS - 1);
        const int base = 4 * hq_l * 36 + s_l;
        const float4 v4 = make_float4(tl[base], tl[base + 36],
                                      tl[base + 72], tl[base + 108]);
        peP[((size_t)(b * 64 + ot * 16 + hq_l)) * NS + s0 + s_l] = v4;
    }
}

// ---------------------------------------------------------------------------
// K2: scores (softmax-shift-invariant):
//   e'[t,s] = sum_h w[h] / (exp2(peP[b][h/4][s].c + pq[t,h]) + 1)
// Packed peP: ONE coalesced f4 load per (lane, h4) iter (1 KB/wave).
// pq/w wave-uniform s_loads; 4 independent acc chains (ILP).
// Block 512 thr = 8 waves = 8 t-rows; lanes = 64 s. Grid (8 sx, 16 ty, 4 b).
// ---------------------------------------------------------------------------
__global__ __launch_bounds__(512) void k2_score(
    const float4* __restrict__ peP, const float* __restrict__ pq,
    const float* __restrict__ w, float* __restrict__ e)
{
    const int sx = blockIdx.x;
    const int ty = blockIdx.y;
    const int b  = blockIdx.z;
    const int lane = threadIdx.x & 63;
    const int wv = __builtin_amdgcn_readfirstlane(threadIdx.x >> 6);
    const int t = ty * 8 + wv;
    const int s = sx * 64 + lane;

    const float4* __restrict__ pqp = reinterpret_cast<const float4*>(
        pq + (size_t)(b * NT + t) * NH);
    const float4* __restrict__ wp = reinterpret_cast<const float4*>(w);
    const float4* __restrict__ pp = peP + (size_t)b * 64 * NS + s;

    float acc0 = 0.f, acc1 = 0.f, acc2 = 0.f, acc3 = 0.f;
#pragma unroll 8
    for (int h4 = 0; h4 < 64; ++h4) {
        const float4 pv = pp[(size_t)h4 * NS];
        const float4 a  = pqp[h4];
        const float4 wl = wp[h4];
        acc0 = fmaf(wl.x, __builtin_amdgcn_rcpf(fast_exp2(pv.x + a.x) + 1.0f), acc0);
        acc1 = fmaf(wl.y, __builtin_amdgcn_rcpf(fast_exp2(pv.y + a.y) + 1.0f), acc1);
        acc2 = fmaf(wl.z, __builtin_amdgcn_rcpf(fast_exp2(pv.z + a.z) + 1.0f), acc2);
        acc3 = fmaf(wl.w, __builtin_amdgcn_rcpf(fast_exp2(pv.w + a.w) + 1.0f), acc3);
    }
    e[(size_t)(b * NT + t) * NS + s] = (acc0 + acc1) + (acc2 + acc3);
}

// ---------------------------------------------------------------------------
// K3: masked softmax + context. Block = 4 independent waves, wave = 1 t-row,
// lanes = 64 h-cols (coalesced enc). Softmax fully in-register; P-row parked
// in LDS for uniform broadcast during context. Grid (4 ht, 32 tt, 4 b).
// ---------------------------------------------------------------------------
__global__ __launch_bounds__(256) void k3_ctx(
    const float* __restrict__ e, const float* __restrict__ enc,
    const int* __restrict__ lens, float* __restrict__ c)
{
    __shared__ float ps[4][NS];

    const int ht = blockIdx.x;
    const int tt = blockIdx.y;
    const int b  = blockIdx.z;
    const int tid  = threadIdx.x;
    const int lane = tid & 63;
    const int wv   = __builtin_amdgcn_readfirstlane(tid >> 6);
    const int t    = tt * 4 + wv;
    const int len  = lens[b];

    const float4* erow = reinterpret_cast<const float4*>(e + (size_t)(b * NT + t) * NS);
    float4 va = erow[lane];
    float4 vb = erow[lane + 64];
    const int c0 = 4 * lane;
    const int c1 = 256 + 4 * lane;
    if (c0 + 0 >= len) va.x = -INFINITY;
    if (c0 + 1 >= len) va.y = -INFINITY;
    if (c0 + 2 >= len) va.z = -INFINITY;
    if (c0 + 3 >= len) va.w = -INFINITY;
    if (c1 + 0 >= len) vb.x = -INFINITY;
    if (c1 + 1 >= len) vb.y = -INFINITY;
    if (c1 + 2 >= len) vb.z = -INFINITY;
    if (c1 + 3 >= len) vb.w = -INFINITY;

    float m = fmaxf(fmaxf(fmaxf(va.x, va.y), fmaxf(va.z, va.w)),
                    fmaxf(fmaxf(vb.x, vb.y), fmaxf(vb.z, vb.w)));
#pragma unroll
    for (int off = 32; off; off >>= 1) m = fmaxf(m, __shfl_xor(m, off));

    va.x = __expf(va.x - m); va.y = __expf(va.y - m);
    va.z = __expf(va.z - m); va.w = __expf(va.w - m);
    vb.x = __expf(vb.x - m); vb.y = __expf(vb.y - m);
    vb.z = __expf(vb.z - m); vb.w = __expf(vb.w - m);

    float sum = va.x + va.y + va.z + va.w + vb.x + vb.y + vb.z + vb.w;
#pragma unroll
    for (int off = 32; off; off >>= 1) sum += __shfl_xor(sum, off);
    const float rsum = 1.0f / sum;

    float4* ps4w = reinterpret_cast<float4*>(&ps[wv][0]);
    ps4w[lane] = va;
    ps4w[lane + 64] = vb;
    __syncthreads();

    const float* ep = enc + (size_t)b * NS * NH + ht * 64 + lane;
    const float4* p4 = reinterpret_cast<const float4*>(&ps[wv][0]);
    float acc0 = 0.f, acc1 = 0.f, acc2 = 0.f, acc3 = 0.f;
#pragma unroll 2
    for (int s4 = 0; s4 < 32; ++s4) {
        {
            const float4 pw = p4[s4];
            const float* eb = ep + (size_t)(4 * s4) * NH;
            acc0 = fmaf(pw.x, eb[0],      acc0);
            acc0 = fmaf(pw.y, eb[NH],     acc0);
            acc0 = fmaf(pw.z, eb[2 * NH], acc0);
            acc0 = fmaf(pw.w, eb[3 * NH], acc0);
        }
        {
            const float4 pw = p4[s4 + 32];
            const float* eb = ep + (size_t)(4 * (s4 + 32)) * NH;
            acc1 = fmaf(pw.x, eb[0],      acc1);
            acc1 = fmaf(pw.y, eb[NH],     acc1);
            acc1 = fmaf(pw.z, eb[2 * NH], acc1);
            acc1 = fmaf(pw.w, eb[3 * NH], acc1);
        }
        {
            const float4 pw = p4[s4 + 64];
            const float* eb = ep + (size_t)(4 * (s4 + 64)) * NH;
            acc2 = fmaf(pw.x, eb[0],      acc2);
            acc2 = fmaf(pw.y, eb[NH],     acc2);
            acc2 = fmaf(pw.z, eb[2 * NH], acc2);
            acc2 = fmaf(pw.w, eb[3 * NH], acc2);
        }
        {
            const float4 pw = p4[s4 + 96];
            const float* eb = ep + (size_t)(4 * (s4 + 96)) * NH;
            acc3 = fmaf(pw.x, eb[0],      acc3);
            acc3 = fmaf(pw.y, eb[NH],     acc3);
            acc3 = fmaf(pw.z, eb[2 * NH], acc3);
            acc3 = fmaf(pw.w, eb[3 * NH], acc3);
        }
    }
    c[(size_t)(b * NT + t) * NH + ht * 64 + lane] =
        (acc0 + acc1 + acc2 + acc3) * rsum;
}

// ---------------------------------------------------------------------------
// K4: out[bt,o] = tanh(cat[bt,:].Wout[o,:]), cat = [q|c]. Lanes = o, Wout
// half-tiles (64 o x 256 k = 64KB) staged swizzled; cat rows wave-uniform
// s_loads. 8 waves = 8 bt rows. Grid 64 bt-tiles x 4 o-tiles = 256 blocks.
// ---------------------------------------------------------------------------
__global__ __launch_bounds__(512) void k4_out(
    const float* __restrict__ qin, const float* __restrict__ cin,
    const float* __restrict__ Wout, float* __restrict__ out)
{
    __shared__ float4 wsh[64 * 64];

    const int ot  = blockIdx.x & 3;
    const int btt = blockIdx.x >> 2;
    const int tid = threadIdx.x;
    const int o   = tid & 63;
    const int wv  = __builtin_amdgcn_readfirstlane(tid >> 6);
    const int bt  = btt * 8 + wv;
    const int osw = o & 7;

    float acc = 0.f;
#pragma unroll
    for (int half = 0; half < 2; ++half) {
        __syncthreads();
        {
            const int row = tid >> 3, jl = tid & 7;
            const float4* src = reinterpret_cast<const float4*>(
                Wout + (size_t)(ot * 64 + row) * (2 * NH) + half * NH);
            const int rsw = row & 7;
#pragma unroll
            for (int kk = 0; kk < 8; ++kk) {
                const int j = jl + 8 * kk;
                wsh[row * 64 + (j ^ rsw)] = src[j];
            }
        }
        __syncthreads();

        const float4* __restrict__ xr = reinterpret_cast<const float4*>(
            (half ? cin : qin) + (size_t)bt * NH);
#pragma unroll 8
        for (int k4 = 0; k4 < 64; ++k4) {
            acc = dot4(wsh[o * 64 + (k4 ^ osw)], xr[k4], acc);
        }
    }
    out[(size_t)bt * NH + ot * 64 + o] = fast_tanh(acc);
}

extern "C" void kernel_launch(void* const* d_in, const int* in_sizes, int n_in,
                              void* d_out, int out_size, void* d_ws, size_t ws_size,
                              hipStream_t stream) {
    const float* q    = (const float*)d_in[0];  // (B,T,H)
    const float* enc  = (const float*)d_in[1];  // (B,S,H)
    const int*   lens = (const int*)d_in[2];    // (B,)
    const float* Ws   = (const float*)d_in[3];  // (H,H)
    const float* Wh   = (const float*)d_in[4];  // (H,H)
    const float* v    = (const float*)d_in[5];  // (H,)
    const float* Wout = (const float*)d_in[6];  // (H,2H)
    float* out = (float*)d_out;                 // (B,T,H)

    float4* peP = (float4*)d_ws;                      // NB*64*NS f4 (=NB*NH*NS fl)
    float* pq  = (float*)d_ws + (size_t)NB * NH * NS; // NB*NT*NH
    float* w   = pq + (size_t)NB * NT * NH;           // NH
    float* e   = w + NH;                              // NB*NT*NS
    float* c   = e + (size_t)NB * NT * NS;            // NB*NT*NH

    k1_proj<<<320, 512, 0, stream>>>(enc, q, Wh, Ws, v, peP, pq, w);
    k2_score<<<dim3(NS / 64, NT / 8, NB), 512, 0, stream>>>(peP, pq, w, e);
    k3_ctx<<<dim3(NH / 64, NT / 4, NB), 256, 0, stream>>>(e, enc, lens, c);
    k4_out<<<256, 512, 0, stream>>>(q, c, Wout, out);
}

// Round 10
// 60.593 us; speedup vs baseline: 2.8729x; 1.0885x over previous
//
#include <hip/hip_runtime.h>
#include <math.h>

#define NB 4
#define NT 128
#define NS 512
#define NH 256

// pe/pq prescaled by 2*log2(e) so exp(2z) == exp2(pe'+pq')
#define SCALE_2LOG2E 2.8853900817779268f

__device__ __forceinline__ float fast_exp2(float x) {
#if __has_builtin(__builtin_amdgcn_exp2f)
    return __builtin_amdgcn_exp2f(x);
#else
    return __expf(x * 0.6931471805599453f);
#endif
}

__device__ __forceinline__ float fast_tanh(float x) {
    // tanh(x) = 1 - 2/(exp(2x)+1); safe at +/-inf
    float e = __expf(2.0f * x);
    return 1.0f - 2.0f / (e + 1.0f);
}

__device__ __forceinline__ float dot4(float4 a, float4 b, float acc) {
    acc = fmaf(a.x, b.x, acc);
    acc = fmaf(a.y, b.y, acc);
    acc = fmaf(a.z, b.z, acc);
    acc = fmaf(a.w, b.w, acc);
    return acc;
}

// ---------------------------------------------------------------------------
// 64x64-tile GEMM core, K chunked by 128, BOTH operands in LDS (no s_load /
// VMEM in the inner loop -> single lgkm domain, compiler pipelines ds_read).
// 256 thr; thread = 4 o-cols x 4 m-rows (16 acc, 64 fma : 8 ds per k4-iter).
// XOR swizzle ((row>>2)&7) on the f4-slot makes compute reads conflict-free.
// ---------------------------------------------------------------------------
__device__ __forceinline__ void gemm_tile_64x64(
    float4* __restrict__ wsh, float4* __restrict__ xsh,   // [64][32] f4 each
    const float* __restrict__ Wp, int wstride,            // 64 rows at o_base
    const float* __restrict__ Xp,                         // 64 rows at m_base
    int kchunks, int tid, float acc[4][4])
{
    const int o0 = (tid & 15) * 4;
    const int m0 = (tid >> 4) * 4;
    const int srow = tid >> 2, sjl = tid & 3;
    const int wslotx = (tid & 7);         // ((o0>>2)&7), uniform over j
    const int xslotx = ((tid >> 4) & 7);  // ((m0>>2)&7), uniform over i

    for (int ck = 0; ck < kchunks; ++ck) {
        __syncthreads();
        // stage W chunk: 64 rows x 32 f4; 4 thr/row x 8 f4
        {
            const float4* src = reinterpret_cast<const float4*>(
                Wp + (size_t)srow * wstride + ck * 128);
            const int rsw = (srow >> 2) & 7;
#pragma unroll
            for (int k = 0; k < 8; ++k) {
                const int j = sjl + 4 * k;
                wsh[srow * 32 + ((j & 31) ^ rsw)] = src[j];
            }
        }
        // stage X chunk
        {
            const float4* src = reinterpret_cast<const float4*>(
                Xp + (size_t)srow * NH + ck * 128);
            const int rsw = (srow >> 2) & 7;
#pragma unroll
            for (int k = 0; k < 8; ++k) {
                const int j = sjl + 4 * k;
                xsh[srow * 32 + ((j & 31) ^ rsw)] = src[j];
            }
        }
        __syncthreads();

#pragma unroll 4
        for (int k4 = 0; k4 < 32; ++k4) {
            float4 wv0 = wsh[(o0 + 0) * 32 + (k4 ^ wslotx)];
            float4 wv1 = wsh[(o0 + 1) * 32 + (k4 ^ wslotx)];
            float4 wv2 = wsh[(o0 + 2) * 32 + (k4 ^ wslotx)];
            float4 wv3 = wsh[(o0 + 3) * 32 + (k4 ^ wslotx)];
            float4 xv0 = xsh[(m0 + 0) * 32 + (k4 ^ xslotx)];
            float4 xv1 = xsh[(m0 + 1) * 32 + (k4 ^ xslotx)];
            float4 xv2 = xsh[(m0 + 2) * 32 + (k4 ^ xslotx)];
            float4 xv3 = xsh[(m0 + 3) * 32 + (k4 ^ xslotx)];
            acc[0][0] = dot4(xv0, wv0, acc[0][0]);
            acc[0][1] = dot4(xv0, wv1, acc[0][1]);
            acc[0][2] = dot4(xv0, wv2, acc[0][2]);
            acc[0][3] = dot4(xv0, wv3, acc[0][3]);
            acc[1][0] = dot4(xv1, wv0, acc[1][0]);
            acc[1][1] = dot4(xv1, wv1, acc[1][1]);
            acc[1][2] = dot4(xv1, wv2, acc[1][2]);
            acc[1][3] = dot4(xv1, wv3, acc[1][3]);
            acc[2][0] = dot4(xv2, wv0, acc[2][0]);
            acc[2][1] = dot4(xv2, wv1, acc[2][1]);
            acc[2][2] = dot4(xv2, wv2, acc[2][2]);
            acc[2][3] = dot4(xv2, wv3, acc[2][3]);
            acc[3][0] = dot4(xv3, wv0, acc[3][0]);
            acc[3][1] = dot4(xv3, wv1, acc[3][1]);
            acc[3][2] = dot4(xv3, wv2, acc[3][2]);
            acc[3][3] = dot4(xv3, wv3, acc[3][3]);
        }
    }
}

// ---------------------------------------------------------------------------
// K1: all projections.
//   bx in [0,128):   pe -> peP[b][h4][s] packed f4-over-h-quad, x SCALE
//   bx in [128,160): pq[r][o] row-major, x SCALE   (bx==128 also w = -2v)
//   bx in [160,192): oq = q . W1^T (W1 = Wout[:, :256]), row-major, x1
// ---------------------------------------------------------------------------
__global__ __launch_bounds__(256) void k1_proj(
    const float* __restrict__ enc, const float* __restrict__ q,
    const float* __restrict__ Wh, const float* __restrict__ Ws,
    const float* __restrict__ Wout, const float* __restrict__ v,
    float4* __restrict__ peP, float* __restrict__ pq,
    float* __restrict__ oq, float* __restrict__ w)
{
    __shared__ float4 wsh[64 * 32];   // 32 KB
    __shared__ float4 xsh[64 * 32];   // 32 KB

    const int bx = blockIdx.x;
    const int tid = threadIdx.x;
    float acc[4][4];
#pragma unroll
    for (int i = 0; i < 4; ++i)
#pragma unroll
        for (int j = 0; j < 4; ++j) acc[i][j] = 0.f;

    if (bx == 128) w[tid] = -2.0f * v[tid];

    const int o0 = (tid & 15) * 4;
    const int m0 = (tid >> 4) * 4;

    if (bx < 128) {
        const int mt = bx >> 2, ot = bx & 3;
        const int m_base = mt * 64;
        gemm_tile_64x64(wsh, xsh, Wh + (size_t)(ot * 64) * NH, NH,
                        enc + (size_t)m_base * NH, 2, tid, acc);
        const int b = m_base >> 9, s_base = m_base & (NS - 1);
        const int quad = ot * 16 + (tid & 15);
#pragma unroll
        for (int i = 0; i < 4; ++i) {
            peP[(size_t)(b * 64 + quad) * NS + s_base + m0 + i] =
                make_float4(acc[i][0] * SCALE_2LOG2E, acc[i][1] * SCALE_2LOG2E,
                            acc[i][2] * SCALE_2LOG2E, acc[i][3] * SCALE_2LOG2E);
        }
    } else if (bx < 160) {
        const int bi = bx - 128;
        const int mt = bi >> 2, ot = bi & 3;
        const int m_base = mt * 64;
        gemm_tile_64x64(wsh, xsh, Ws + (size_t)(ot * 64) * NH, NH,
                        q + (size_t)m_base * NH, 2, tid, acc);
#pragma unroll
        for (int i = 0; i < 4; ++i) {
            *reinterpret_cast<float4*>(
                pq + (size_t)(m_base + m0 + i) * NH + ot * 64 + o0) =
                make_float4(acc[i][0] * SCALE_2LOG2E, acc[i][1] * SCALE_2LOG2E,
                            acc[i][2] * SCALE_2LOG2E, acc[i][3] * SCALE_2LOG2E);
        }
    } else {
        const int bi = bx - 160;
        const int mt = bi >> 2, ot = bi & 3;
        const int m_base = mt * 64;
        gemm_tile_64x64(wsh, xsh, Wout + (size_t)(ot * 64) * (2 * NH), 2 * NH,
                        q + (size_t)m_base * NH, 2, tid, acc);
#pragma unroll
        for (int i = 0; i < 4; ++i) {
            *reinterpret_cast<float4*>(
                oq + (size_t)(m_base + m0 + i) * NH + ot * 64 + o0) =
                make_float4(acc[i][0], acc[i][1], acc[i][2], acc[i][3]);
        }
    }
}

// ---------------------------------------------------------------------------
// K2: scores e'[t,s] = sum_h w[h]/(exp2(peP[b][h/4][s].c + pq[t,h]) + 1).
// ALL operands LDS-staged (peP slice 64KB + pq rows 8KB + w 1KB = 73KB,
// 2 blocks/CU). Inner loop: 3 conflict-free ds_read + VALU/trans only.
// Block 512 thr = 8 waves = 8 t-rows; lanes = 64 s. Grid (8 sx, 16 ty, 4 b).
// ---------------------------------------------------------------------------
__global__ __launch_bounds__(512) void k2_score(
    const float4* __restrict__ peP, const float* __restrict__ pq,
    const float* __restrict__ w, float* __restrict__ e)
{
    __shared__ float4 pp[64 * 64];   // 64 KB
    __shared__ float4 pqs[8 * 64];   // 8 KB
    __shared__ float4 wls[64];       // 1 KB

    const int sx = blockIdx.x;
    const int ty = blockIdx.y;
    const int b  = blockIdx.z;
    const int tid = threadIdx.x;
    const int t0 = ty * 8;

    // stage peP slice: 64 h4-rows x 64 s-f4; 8 thr/row x 8 f4
    {
        const int row = tid >> 3, jl = tid & 7;
        const float4* src = peP + (size_t)(b * 64 + row) * NS + sx * 64;
#pragma unroll
        for (int k = 0; k < 8; ++k) {
            const int j = jl + 8 * k;
            pp[row * 64 + j] = src[j];
        }
    }
    // stage pq rows t0..t0+7: 8 rows x 64 f4 = 512 f4, 1 per thread
    {
        const int r = tid >> 6, j = tid & 63;
        pqs[r * 64 + j] = reinterpret_cast<const float4*>(
            pq + (size_t)(b * NT + t0 + r) * NH)[j];
    }
    if (tid < 64) wls[tid] = reinterpret_cast<const float4*>(w)[tid];
    __syncthreads();

    const int lane = tid & 63;
    const int wvi  = tid >> 6;   // t_local

    float acc0 = 0.f, acc1 = 0.f, acc2 = 0.f, acc3 = 0.f;
#pragma unroll 8
    for (int h4 = 0; h4 < 64; ++h4) {
        const float4 pv = pp[h4 * 64 + lane];
        const float4 aq = pqs[wvi * 64 + h4];
        const float4 wl = wls[h4];
        acc0 = fmaf(wl.x, __builtin_amdgcn_rcpf(fast_exp2(pv.x + aq.x) + 1.0f), acc0);
        acc1 = fmaf(wl.y, __builtin_amdgcn_rcpf(fast_exp2(pv.y + aq.y) + 1.0f), acc1);
        acc2 = fmaf(wl.z, __builtin_amdgcn_rcpf(fast_exp2(pv.z + aq.z) + 1.0f), acc2);
        acc3 = fmaf(wl.w, __builtin_amdgcn_rcpf(fast_exp2(pv.w + aq.w) + 1.0f), acc3);
    }
    e[(size_t)(b * NT + t0 + wvi) * NS + sx * 64 + lane] = (acc0 + acc1) + (acc2 + acc3);
}

// ---------------------------------------------------------------------------
// K3: masked softmax + context (unchanged from R9 — control).
// ---------------------------------------------------------------------------
__global__ __launch_bounds__(256) void k3_ctx(
    const float* __restrict__ e, const float* __restrict__ enc,
    const int* __restrict__ lens, float* __restrict__ c)
{
    __shared__ float ps[4][NS];

    const int ht = blockIdx.x;
    const int tt = blockIdx.y;
    const int b  = blockIdx.z;
    const int tid  = threadIdx.x;
    const int lane = tid & 63;
    const int wv   = __builtin_amdgcn_readfirstlane(tid >> 6);
    const int t    = tt * 4 + wv;
    const int len  = lens[b];

    const float4* erow = reinterpret_cast<const float4*>(e + (size_t)(b * NT + t) * NS);
    float4 va = erow[lane];
    float4 vb = erow[lane + 64];
    const int c0 = 4 * lane;
    const int c1 = 256 + 4 * lane;
    if (c0 + 0 >= len) va.x = -INFINITY;
    if (c0 + 1 >= len) va.y = -INFINITY;
    if (c0 + 2 >= len) va.z = -INFINITY;
    if (c0 + 3 >= len) va.w = -INFINITY;
    if (c1 + 0 >= len) vb.x = -INFINITY;
    if (c1 + 1 >= len) vb.y = -INFINITY;
    if (c1 + 2 >= len) vb.z = -INFINITY;
    if (c1 + 3 >= len) vb.w = -INFINITY;

    float m = fmaxf(fmaxf(fmaxf(va.x, va.y), fmaxf(va.z, va.w)),
                    fmaxf(fmaxf(vb.x, vb.y), fmaxf(vb.z, vb.w)));
#pragma unroll
    for (int off = 32; off; off >>= 1) m = fmaxf(m, __shfl_xor(m, off));

    va.x = __expf(va.x - m); va.y = __expf(va.y - m);
    va.z = __expf(va.z - m); va.w = __expf(va.w - m);
    vb.x = __expf(vb.x - m); vb.y = __expf(vb.y - m);
    vb.z = __expf(vb.z - m); vb.w = __expf(vb.w - m);

    float sum = va.x + va.y + va.z + va.w + vb.x + vb.y + vb.z + vb.w;
#pragma unroll
    for (int off = 32; off; off >>= 1) sum += __shfl_xor(sum, off);
    const float rsum = 1.0f / sum;

    float4* ps4w = reinterpret_cast<float4*>(&ps[wv][0]);
    ps4w[lane] = va;
    ps4w[lane + 64] = vb;
    __syncthreads();

    const float* ep = enc + (size_t)b * NS * NH + ht * 64 + lane;
    const float4* p4 = reinterpret_cast<const float4*>(&ps[wv][0]);
    float acc0 = 0.f, acc1 = 0.f, acc2 = 0.f, acc3 = 0.f;
#pragma unroll 2
    for (int s4 = 0; s4 < 32; ++s4) {
        {
            const float4 pw = p4[s4];
            const float* eb = ep + (size_t)(4 * s4) * NH;
            acc0 = fmaf(pw.x, eb[0],      acc0);
            acc0 = fmaf(pw.y, eb[NH],     acc0);
            acc0 = fmaf(pw.z, eb[2 * NH], acc0);
            acc0 = fmaf(pw.w, eb[3 * NH], acc0);
        }
        {
            const float4 pw = p4[s4 + 32];
            const float* eb = ep + (size_t)(4 * (s4 + 32)) * NH;
            acc1 = fmaf(pw.x, eb[0],      acc1);
            acc1 = fmaf(pw.y, eb[NH],     acc1);
            acc1 = fmaf(pw.z, eb[2 * NH], acc1);
            acc1 = fmaf(pw.w, eb[3 * NH], acc1);
        }
        {
            const float4 pw = p4[s4 + 64];
            const float* eb = ep + (size_t)(4 * (s4 + 64)) * NH;
            acc2 = fmaf(pw.x, eb[0],      acc2);
            acc2 = fmaf(pw.y, eb[NH],     acc2);
            acc2 = fmaf(pw.z, eb[2 * NH], acc2);
            acc2 = fmaf(pw.w, eb[3 * NH], acc2);
        }
        {
            const float4 pw = p4[s4 + 96];
            const float* eb = ep + (size_t)(4 * (s4 + 96)) * NH;
            acc3 = fmaf(pw.x, eb[0],      acc3);
            acc3 = fmaf(pw.y, eb[NH],     acc3);
            acc3 = fmaf(pw.z, eb[2 * NH], acc3);
            acc3 = fmaf(pw.w, eb[3 * NH], acc3);
        }
    }
    c[(size_t)(b * NT + t) * NH + ht * 64 + lane] =
        (acc0 + acc1 + acc2 + acc3) * rsum;
}

// ---------------------------------------------------------------------------
// K4: out = tanh(oq + c.W2^T), W2 = Wout[:, 256:]. Same 64x64 LDS template;
// m = bt rows. 32 blocks.
// ---------------------------------------------------------------------------
__global__ __launch_bounds__(256) void k4_out(
    const float* __restrict__ cin, const float* __restrict__ Wout,
    const float* __restrict__ oq, float* __restrict__ out)
{
    __shared__ float4 wsh[64 * 32];
    __shared__ float4 xsh[64 * 32];

    const int bx = blockIdx.x;
    const int tid = threadIdx.x;
    const int mt = bx >> 2, ot = bx & 3;
    const int m_base = mt * 64;
    const int o0 = (tid & 15) * 4;
    const int m0 = (tid >> 4) * 4;

    float acc[4][4];
#pragma unroll
    for (int i = 0; i < 4; ++i)
#pragma unroll
        for (int j = 0; j < 4; ++j) acc[i][j] = 0.f;

    gemm_tile_64x64(wsh, xsh, Wout + (size_t)(ot * 64) * (2 * NH) + NH, 2 * NH,
                    cin + (size_t)m_base * NH, 2, tid, acc);

#pragma unroll
    for (int i = 0; i < 4; ++i) {
        const float4 qo = *reinterpret_cast<const float4*>(
            oq + (size_t)(m_base + m0 + i) * NH + ot * 64 + o0);
        float4 r;
        r.x = fast_tanh(acc[i][0] + qo.x);
        r.y = fast_tanh(acc[i][1] + qo.y);
        r.z = fast_tanh(acc[i][2] + qo.z);
        r.w = fast_tanh(acc[i][3] + qo.w);
        *reinterpret_cast<float4*>(
            out + (size_t)(m_base + m0 + i) * NH + ot * 64 + o0) = r;
    }
}

extern "C" void kernel_launch(void* const* d_in, const int* in_sizes, int n_in,
                              void* d_out, int out_size, void* d_ws, size_t ws_size,
                              hipStream_t stream) {
    const float* q    = (const float*)d_in[0];  // (B,T,H)
    const float* enc  = (const float*)d_in[1];  // (B,S,H)
    const int*   lens = (const int*)d_in[2];    // (B,)
    const float* Ws   = (const float*)d_in[3];  // (H,H)
    const float* Wh   = (const float*)d_in[4];  // (H,H)
    const float* v    = (const float*)d_in[5];  // (H,)
    const float* Wout = (const float*)d_in[6];  // (H,2H)
    float* out = (float*)d_out;                 // (B,T,H)

    float4* peP = (float4*)d_ws;                       // NB*64*NS f4
    float* pq  = (float*)d_ws + (size_t)NB * NH * NS;  // NB*NT*NH
    float* oq  = pq + (size_t)NB * NT * NH;            // NB*NT*NH
    float* w   = oq + (size_t)NB * NT * NH;            // NH
    float* e   = w + NH;                               // NB*NT*NS
    float* c   = e + (size_t)NB * NT * NS;             // NB*NT*NH

    k1_proj<<<192, 256, 0, stream>>>(enc, q, Wh, Ws, Wout, v, peP, pq, oq, w);
    k2_score<<<dim3(NS / 64, NT / 8, NB), 512, 0, stream>>>(peP, pq, w, e);
    k3_ctx<<<dim3(NH / 64, NT / 4, NB), 256, 0, stream>>>(e, enc, lens, c);
    k4_out<<<32, 256, 0, stream>>>(c, Wout, oq, out);
}